// Round 2
// baseline (609.173 us; speedup 1.0000x reference)
//
#include <hip/hip_runtime.h>
#include <math.h>

#define HW 4096
#define PLSTRIDE ((size_t)HW * 8)   // elements per 8-channel plane of A

typedef unsigned short ushort_t;
typedef short v8s __attribute__((ext_vector_type(8)));
typedef float v4f __attribute__((ext_vector_type(4)));

__device__ __forceinline__ float bf2f(ushort_t u) {
    union { unsigned int i; float f; } v; v.i = ((unsigned int)u) << 16; return v.f;
}
__device__ __forceinline__ ushort_t f2bf(float f) {
    unsigned int x = __float_as_uint(f);
    x += 0x7fffu + ((x >> 16) & 1u);   // RNE
    return (ushort_t)(x >> 16);
}

// async global->LDS, 16B per lane; LDS dest = wave-uniform base + lane*16
__device__ __forceinline__ void gld16(const ushort_t* g, ushort_t* l) {
    __builtin_amdgcn_global_load_lds(
        (__attribute__((address_space(1))) void*)g,
        (__attribute__((address_space(3))) void*)l, 16, 0, 0);
}

// ---------------- per-channel constants -------------------------------------
// cbuf layout (floats): [0]=sE [256]=cE [512]=s1 [768]=c1 [1024]=s2 [1280]=c2
__global__ __launch_bounds__(256) void k_consts(
    const float* eg, const float* ebt, const float* em, const float* ev,
    const float* fb,
    const float* g1, const float* b1, const float* m1, const float* v1,
    const float* balb,
    const float* g2, const float* b2, const float* m2, const float* v2,
    float* cbuf)
{
    int c = threadIdx.x;
    float iE = eg[c] * rsqrtf(ev[c] + 1e-5f);
    cbuf[c]       = iE;
    cbuf[256 + c] = ebt[c] - em[c] * iE;
    float i1 = g1[c] * rsqrtf(v1[c] + 1e-5f);
    cbuf[512 + c] = i1;
    cbuf[768 + c] = b1[c] - m1[c] * i1 + fb[c] * i1;
    float i2 = g2[c] * rsqrtf(v2[c] + 1e-5f);
    cbuf[1024 + c] = i2;
    cbuf[1280 + c] = b2[c] - m2[c] * i2 + balb[c] * i2;
}

// ---------------- bf16 copies of shared weights -----------------------------
__global__ __launch_bounds__(256) void k_wcopy(const float* fusw, const float* balw,
                                               ushort_t* fusw2b, ushort_t* balwb)
{
    int o = blockIdx.x, t = threadIdx.x;
    fusw2b[o * 256 + t] = f2bf(fusw[o * 512 + 256 + t]);
    balwb[o * 256 + t]  = f2bf(balw[o * 256 + t]);
}

// ---------------- edge dw3x3+BN+relu, bf16(x) copy, SE avg ------------------
// Writes A in blocked layout: plane (b*64+cg) = bf16(x) chunk, plane
// (b*64+32+cg) = edge chunk; chunk = 8 channels x 2B = 16B, hw-major.
// block: 512 thr = 8 ch-planes x 64 w; grid (32 cg, 32 b). LDS transpose
// per 8 h-rows so global writes are dense 16B/lane.
__global__ __launch_bounds__(512) void k_edge(const float* x, const float* ew,
                                              const float* cbuf, ushort_t* A,
                                              float* avg)
{
    __shared__ __align__(16) ushort_t Xs[4096];   // [8h][64w][8c]
    __shared__ __align__(16) ushort_t Es[4096];
    int cg = blockIdx.x;
    int b = blockIdx.y;
    int t = threadIdx.x;
    int w = t & 63;
    int pl = t >> 6;                    // wave index = channel within group
    int c = cg * 8 + pl;
    const float* px = x + ((size_t)(b * 256 + c)) * HW;
    ushort_t* AX = A + ((size_t)(b * 64 + cg)) * PLSTRIDE;
    ushort_t* AE = A + ((size_t)(b * 64 + 32 + cg)) * PLSTRIDE;
    float wt[9];
    #pragma unroll
    for (int k = 0; k < 9; ++k) wt[k] = ew[c * 9 + k];
    float sE = cbuf[c], cE = cbuf[256 + c];
    bool wl = (w > 0), wrr = (w < 63);

    float p0l = 0.f, p0c = 0.f, p0r = 0.f;
    float p1l, p1c, p1r;
    p1c = px[w];
    p1l = wl ? px[w - 1] : 0.f;
    p1r = wrr ? px[w + 1] : 0.f;
    float s = 0.f;
    for (int hb = 0; hb < 8; ++hb) {
        #pragma unroll
        for (int hi = 0; hi < 8; ++hi) {
            int h = hb * 8 + hi;
            float p2l, p2c, p2r;
            if (h < 63) {
                const float* row = px + (h + 1) * 64;
                p2c = row[w];
                p2l = wl ? row[w - 1] : 0.f;
                p2r = wrr ? row[w + 1] : 0.f;
            } else {
                p2l = p2c = p2r = 0.f;
            }
            float a = p0l * wt[0] + p0c * wt[1] + p0r * wt[2]
                    + p1l * wt[3] + p1c * wt[4] + p1r * wt[5]
                    + p2l * wt[6] + p2c * wt[7] + p2r * wt[8];
            s += p1c;
            float v = a * sE + cE;
            Es[hi * 512 + w * 8 + pl] = f2bf(v > 0.f ? v : 0.f);
            Xs[hi * 512 + w * 8 + pl] = f2bf(p1c);
            p0l = p1l; p0c = p1c; p0r = p1r;
            p1l = p2l; p1c = p2c; p1r = p2r;
        }
        __syncthreads();
        {
            // flush: thread t -> (hh=pl, ww=w); dense 16B stores, lane-contig
            int hwg = (hb * 8 + pl) * 64 + w;
            uint4 vx = *(const uint4*)&Xs[pl * 512 + w * 8];
            uint4 ve = *(const uint4*)&Es[pl * 512 + w * 8];
            *(uint4*)(AX + (size_t)hwg * 8) = vx;
            *(uint4*)(AE + (size_t)hwg * 8) = ve;
        }
        __syncthreads();
    }
    #pragma unroll
    for (int off = 32; off > 0; off >>= 1) s += __shfl_down(s, off, 64);
    if ((t & 63) == 0) avg[b * 256 + c] = s * (1.0f / HW);
}

// ---------------- SE MLP + fold att into fusion_w[:, :256] (bf16) -----------
__global__ __launch_bounds__(256) void k_sefold(const float* avg, const float* fc1,
                                                const float* fc2, const float* fusw,
                                                ushort_t* w1b)
{
    int b = blockIdx.x, t = threadIdx.x;
    __shared__ float av[256];
    __shared__ float hid[16];
    av[t] = avg[b * 256 + t];
    __syncthreads();
    if (t < 16) {
        float h = 0.f;
        for (int c = 0; c < 256; ++c) h += av[c] * fc1[t * 256 + c];
        hid[t] = h > 0.f ? h : 0.f;
    }
    __syncthreads();
    float a = 0.f;
    #pragma unroll
    for (int j = 0; j < 16; ++j) a += hid[j] * fc2[t * 16 + j];
    float att = 1.0f / (1.0f + expf(-a));
    ushort_t* wout = w1b + (size_t)b * 65536;
    for (int o = 0; o < 256; ++o)
        wout[o * 256 + t] = f2bf(fusw[o * 512 + t] * att);
}

// ---------------- GEMM1: 128hw x 256o, K=512, in-place into edge planes ----
// global_load_lds staging (pre-swizzled source), double-buffered LDS,
// B-fragment prefetch, one barrier per K-step. 512 thr = 8 waves (2M x 4N).
__global__ __launch_bounds__(512) void k_gemm1(ushort_t* A, const ushort_t* w1b,
                                               const ushort_t* fusw2b,
                                               const float* cbuf)
{
    __shared__ __align__(16) ushort_t At[2][128 * 64];
    int hw0 = blockIdx.x * 128;
    int b = blockIdx.y;
    int t = threadIdx.x;
    int lane = t & 63, wv = t >> 6;
    int quad = lane >> 4, l16 = lane & 15;
    int wr = wv >> 2, wc = wv & 3;

    v4f acc[4][4];
    #pragma unroll
    for (int i = 0; i < 4; ++i)
        #pragma unroll
        for (int j = 0; j < 4; ++j) acc[i][j] = (v4f){0.f, 0.f, 0.f, 0.f};

    const ushort_t* rowA[4];
    const ushort_t* rowB[4];
    int oo[4];
    #pragma unroll
    for (int nt = 0; nt < 4; ++nt) {
        int o = wc * 64 + nt * 16 + l16;
        oo[nt] = o;
        rowA[nt] = w1b + ((size_t)(b * 256 + o)) * 256;
        rowB[nt] = fusw2b + (size_t)o * 256;
    }

    // staging: wave wv covers rows [wv*16, wv*16+16); lane -> (row, chunk)
    // with XOR swizzle on the GLOBAL side so LDS slot jj holds chunk jj^(m&7)
    int mrow0 = wv * 16 + (lane >> 3);
    int cswz = (lane & 7) ^ (mrow0 & 7);
    const ushort_t* srcK = A + ((size_t)(b * 64 + cswz)) * PLSTRIDE
                             + ((size_t)(hw0 + mrow0)) * 8;

#define STAGE1(bs, kbv) { \
    const ushort_t* sp = srcK + (size_t)((kbv) * 8) * PLSTRIDE; \
    gld16(sp, &At[bs][(wv * 16) * 64]); \
    gld16(sp + 64, &At[bs][(wv * 16 + 8) * 64]); }

#define LDB1(dst, kbv) { \
    _Pragma("unroll") for (int ks2 = 0; ks2 < 2; ++ks2) { \
        int kg = (kbv) * 64 + ks2 * 32 + quad * 8; \
        _Pragma("unroll") for (int nt = 0; nt < 4; ++nt) { \
            dst[ks2][nt] = ((kbv) < 4) ? *(const v8s*)(rowA[nt] + kg) \
                                       : *(const v8s*)(rowB[nt] + (kg - 256)); \
        } } }

#define COMP1(bs, bsrc) { \
    _Pragma("unroll") for (int ks2 = 0; ks2 < 2; ++ks2) { \
        v8s afr[4]; \
        _Pragma("unroll") for (int mt = 0; mt < 4; ++mt) { \
            int ml = wr * 64 + mt * 16 + l16; \
            int jj = (ks2 * 4 + quad) ^ (ml & 7); \
            afr[mt] = *(const v8s*)(&At[bs][ml * 64 + jj * 8]); \
        } \
        _Pragma("unroll") for (int mt = 0; mt < 4; ++mt) \
            _Pragma("unroll") for (int nt = 0; nt < 4; ++nt) \
                acc[mt][nt] = __builtin_amdgcn_mfma_f32_16x16x32_bf16( \
                    afr[mt], bsrc[ks2][nt], acc[mt][nt], 0, 0, 0); \
    } }

    v8s bq0[2][4], bq1[2][4];
    LDB1(bq0, 0);
    STAGE1(0, 0);
    __syncthreads();
    #pragma unroll
    for (int kb = 0; kb < 8; ++kb) {
        if ((kb & 1) == 0) {
            if (kb < 7) { STAGE1(1, kb + 1); LDB1(bq1, kb + 1); }
            COMP1(0, bq0);
        } else {
            if (kb < 7) { STAGE1(0, kb + 1); LDB1(bq0, kb + 1); }
            COMP1(1, bq1);
        }
        __syncthreads();
    }
#undef STAGE1
#undef LDB1
#undef COMP1

    // epilogue: bn1, write t1 into edge planes of OWN rows (all reads done)
    #pragma unroll
    for (int nt = 0; nt < 4; ++nt) {
        int o = oo[nt];
        float s1 = cbuf[512 + o], c1 = cbuf[768 + o];
        ushort_t* op = A + ((size_t)(b * 64 + 32 + (o >> 3))) * PLSTRIDE + (o & 7);
        #pragma unroll
        for (int mt = 0; mt < 4; ++mt)
            #pragma unroll
            for (int r = 0; r < 4; ++r) {
                int m = hw0 + wr * 64 + mt * 16 + quad * 4 + r;
                op[(size_t)m * 8] = f2bf(acc[mt][nt][r] * s1 + c1);
            }
    }
}

// ---------------- depthwise 3x3 on blocked layout: E-planes -> X-planes -----
// block: 256 thr = 8 w-chunks x 32 ch-groups; grid (64 h, 32 b).
__global__ __launch_bounds__(256) void k_dw2(ushort_t* A, const float* dfw)
{
    int h = blockIdx.x;
    int b = blockIdx.y;
    int t = threadIdx.x;
    int wc = t & 7;
    int cg = t >> 3;
    int c0 = cg * 8;
    int w0 = wc * 8;

    float acc[8][8];   // [w][ch]
    #pragma unroll
    for (int w = 0; w < 8; ++w)
        #pragma unroll
        for (int ch = 0; ch < 8; ++ch) acc[w][ch] = 0.f;

    const ushort_t* pE = A + ((size_t)(b * 64 + 32 + cg)) * PLSTRIDE;
    #pragma unroll
    for (int r = 0; r < 3; ++r) {
        int hh = h - 1 + r;
        if (hh < 0 || hh > 63) continue;
        float wtr[3][8];
        #pragma unroll
        for (int d = 0; d < 3; ++d)
            #pragma unroll
            for (int ch = 0; ch < 8; ++ch)
                wtr[d][ch] = dfw[(c0 + ch) * 9 + r * 3 + d];
        const ushort_t* row = pE + (size_t)(hh * 64) * 8;
        uint4 rv[10];
        #pragma unroll
        for (int j = 0; j < 10; ++j) {
            int col = w0 - 1 + j;
            if (col >= 0 && col < 64)
                rv[j] = *(const uint4*)(row + (size_t)col * 8);
            else
                rv[j] = (uint4){0u, 0u, 0u, 0u};
        }
        #pragma unroll
        for (int j = 0; j < 10; ++j) {
            unsigned int wd[4] = { rv[j].x, rv[j].y, rv[j].z, rv[j].w };
            float v[8];
            #pragma unroll
            for (int i = 0; i < 8; ++i)
                v[i] = bf2f((i & 1) ? (ushort_t)(wd[i >> 1] >> 16)
                                    : (ushort_t)(wd[i >> 1] & 0xffff));
            if (j <= 7)
                #pragma unroll
                for (int ch = 0; ch < 8; ++ch) acc[j][ch] += v[ch] * wtr[0][ch];
            if (j >= 1 && j <= 8)
                #pragma unroll
                for (int ch = 0; ch < 8; ++ch) acc[j - 1][ch] += v[ch] * wtr[1][ch];
            if (j >= 2)
                #pragma unroll
                for (int ch = 0; ch < 8; ++ch) acc[j - 2][ch] += v[ch] * wtr[2][ch];
        }
    }
    ushort_t* pX = A + ((size_t)(b * 64 + cg)) * PLSTRIDE + (size_t)(h * 64 + w0) * 8;
    #pragma unroll
    for (int w = 0; w < 8; ++w) {
        uint4 ov;
        ov.x = (unsigned int)f2bf(acc[w][0]) | ((unsigned int)f2bf(acc[w][1]) << 16);
        ov.y = (unsigned int)f2bf(acc[w][2]) | ((unsigned int)f2bf(acc[w][3]) << 16);
        ov.z = (unsigned int)f2bf(acc[w][4]) | ((unsigned int)f2bf(acc[w][5]) << 16);
        ov.w = (unsigned int)f2bf(acc[w][6]) | ((unsigned int)f2bf(acc[w][7]) << 16);
        *(uint4*)(pX + (size_t)w * 8) = ov;
    }
}

// ---------------- GEMM2: 128hw x 256o, K=256, X-planes -> E-planes ----------
__global__ __launch_bounds__(512) void k_gemm2(ushort_t* A, const ushort_t* balwb)
{
    __shared__ __align__(16) ushort_t At[2][128 * 64];
    int hw0 = blockIdx.x * 128;
    int b = blockIdx.y;
    int t = threadIdx.x;
    int lane = t & 63, wv = t >> 6;
    int quad = lane >> 4, l16 = lane & 15;
    int wr = wv >> 2, wc = wv & 3;

    v4f acc[4][4];
    #pragma unroll
    for (int i = 0; i < 4; ++i)
        #pragma unroll
        for (int j = 0; j < 4; ++j) acc[i][j] = (v4f){0.f, 0.f, 0.f, 0.f};

    const ushort_t* rowW[4];
    int oo[4];
    #pragma unroll
    for (int nt = 0; nt < 4; ++nt) {
        int o = wc * 64 + nt * 16 + l16;
        oo[nt] = o;
        rowW[nt] = balwb + (size_t)o * 256;
    }

    int mrow0 = wv * 16 + (lane >> 3);
    int cswz = (lane & 7) ^ (mrow0 & 7);
    const ushort_t* srcK = A + ((size_t)(b * 64 + cswz)) * PLSTRIDE
                             + ((size_t)(hw0 + mrow0)) * 8;

#define STAGE2(bs, kbv) { \
    const ushort_t* sp = srcK + (size_t)((kbv) * 8) * PLSTRIDE; \
    gld16(sp, &At[bs][(wv * 16) * 64]); \
    gld16(sp + 64, &At[bs][(wv * 16 + 8) * 64]); }

#define LDB2(dst, kbv) { \
    _Pragma("unroll") for (int ks2 = 0; ks2 < 2; ++ks2) { \
        int kg = (kbv) * 64 + ks2 * 32 + quad * 8; \
        _Pragma("unroll") for (int nt = 0; nt < 4; ++nt) \
            dst[ks2][nt] = *(const v8s*)(rowW[nt] + kg); \
    } }

#define COMP2(bs, bsrc) { \
    _Pragma("unroll") for (int ks2 = 0; ks2 < 2; ++ks2) { \
        v8s afr[4]; \
        _Pragma("unroll") for (int mt = 0; mt < 4; ++mt) { \
            int ml = wr * 64 + mt * 16 + l16; \
            int jj = (ks2 * 4 + quad) ^ (ml & 7); \
            afr[mt] = *(const v8s*)(&At[bs][ml * 64 + jj * 8]); \
        } \
        _Pragma("unroll") for (int mt = 0; mt < 4; ++mt) \
            _Pragma("unroll") for (int nt = 0; nt < 4; ++nt) \
                acc[mt][nt] = __builtin_amdgcn_mfma_f32_16x16x32_bf16( \
                    afr[mt], bsrc[ks2][nt], acc[mt][nt], 0, 0, 0); \
    } }

    v8s bq0[2][4], bq1[2][4];
    LDB2(bq0, 0);
    STAGE2(0, 0);
    __syncthreads();
    #pragma unroll
    for (int kb = 0; kb < 4; ++kb) {
        if ((kb & 1) == 0) {
            if (kb < 3) { STAGE2(1, kb + 1); LDB2(bq1, kb + 1); }
            COMP2(0, bq0);
        } else {
            if (kb < 3) { STAGE2(0, kb + 1); LDB2(bq0, kb + 1); }
            COMP2(1, bq1);
        }
        __syncthreads();
    }
#undef STAGE2
#undef LDB2
#undef COMP2

    #pragma unroll
    for (int nt = 0; nt < 4; ++nt) {
        int o = oo[nt];
        ushort_t* op = A + ((size_t)(b * 64 + 32 + (o >> 3))) * PLSTRIDE + (o & 7);
        #pragma unroll
        for (int mt = 0; mt < 4; ++mt)
            #pragma unroll
            for (int r = 0; r < 4; ++r) {
                int m = hw0 + wr * 64 + mt * 16 + quad * 4 + r;
                op[(size_t)m * 8] = f2bf(acc[mt][nt][r]);
            }
    }
}

// ---------------- final: blocked->NCHW transpose + BN2 + gate by x ----------
__global__ __launch_bounds__(256) void k_final(const ushort_t* A, const float* x,
                                               const float* cbuf, float* out)
{
    __shared__ float Lt[64 * 65];
    int bid = blockIdx.x;
    int b = bid >> 8;
    int rem = bid & 255;
    int hw0 = (rem >> 2) * 64;
    int c0 = (rem & 3) * 64;
    int t = threadIdx.x;
    #pragma unroll
    for (int r = 0; r < 2; ++r) {
        int idx = r * 256 + t;
        int hwl = idx >> 3;
        int cq = idx & 7;
        uint4 v = *(const uint4*)(A + ((size_t)(b * 64 + 32 + (c0 >> 3) + cq)) * PLSTRIDE
                                    + (size_t)(hw0 + hwl) * 8);
        unsigned int wd[4] = { v.x, v.y, v.z, v.w };
        #pragma unroll
        for (int j = 0; j < 8; ++j) {
            ushort_t u = (j & 1) ? (ushort_t)(wd[j >> 1] >> 16) : (ushort_t)(wd[j >> 1] & 0xffff);
            Lt[(cq * 8 + j) * 65 + hwl] = bf2f(u);
        }
    }
    __syncthreads();
    int hw_l = t & 63;
    int c_l0 = t >> 6;
    #pragma unroll
    for (int j = 0; j < 16; ++j) {
        int c_l = c_l0 * 16 + j;
        int c = c0 + c_l;
        float s2 = cbuf[1024 + c], c2 = cbuf[1280 + c];
        size_t g = ((size_t)b * 256 + c) * HW + hw0 + hw_l;
        float xv = x[g];
        out[g] = (Lt[c_l * 65 + hw_l] * s2 + c2) * xv;
    }
}

extern "C" void kernel_launch(void* const* d_in, const int* in_sizes, int n_in,
                              void* d_out, int out_size, void* d_ws, size_t ws_size,
                              hipStream_t stream)
{
    const float* x    = (const float*)d_in[0];
    const float* ew   = (const float*)d_in[1];
    const float* fc1  = (const float*)d_in[6];
    const float* fc2  = (const float*)d_in[7];
    const float* fusw = (const float*)d_in[8];
    const float* dfw  = (const float*)d_in[14];
    const float* balw = (const float*)d_in[15];
    float* out = (float*)d_out;

    // Workspace: A blocked activations 128MiB at 0 (in-place for t1/t2/t3),
    // then weights/scratch — identical total footprint to previous version.
    char* ws = (char*)d_ws;
    ushort_t* A      = (ushort_t*)(ws);                 // 134217728 B
    ushort_t* w1b    = (ushort_t*)(ws + 134217728);     // 4 MiB
    ushort_t* fusw2b = (ushort_t*)(ws + 138412032);     // 128 KiB
    ushort_t* balwb  = (ushort_t*)(ws + 138543104);     // 128 KiB
    float*    avg    = (float*)(ws + 138674176);        // 32 KiB
    float*    cbuf   = (float*)(ws + 138706944);        // 6 KiB

    k_consts<<<1, 256, 0, stream>>>((const float*)d_in[2], (const float*)d_in[3],
                                    (const float*)d_in[4], (const float*)d_in[5],
                                    (const float*)d_in[9],
                                    (const float*)d_in[10], (const float*)d_in[11],
                                    (const float*)d_in[12], (const float*)d_in[13],
                                    (const float*)d_in[16],
                                    (const float*)d_in[17], (const float*)d_in[18],
                                    (const float*)d_in[19], (const float*)d_in[20],
                                    cbuf);
    k_wcopy<<<256, 256, 0, stream>>>(fusw, balw, fusw2b, balwb);
    k_edge<<<dim3(32, 32), 512, 0, stream>>>(x, ew, cbuf, A, avg);
    k_sefold<<<32, 256, 0, stream>>>(avg, fc1, fc2, fusw, w1b);
    k_gemm1<<<dim3(32, 32), 512, 0, stream>>>(A, w1b, fusw2b, cbuf);
    k_dw2<<<dim3(64, 32), 256, 0, stream>>>(A, dfw);
    k_gemm2<<<dim3(32, 32), 512, 0, stream>>>(A, balwb);
    k_final<<<8192, 256, 0, stream>>>(A, x, cbuf, out);
}